// Round 8
// baseline (266.285 us; speedup 1.0000x reference)
//
#include <hip/hip_runtime.h>
#include <math.h>

// DTW 2048x2048, single workgroup of 256 threads (4 waves).
// Lane owns 8 columns; row-blocks of BR=8 rows.
// vs R7: (1) tg/psA/psB pinned in VGPRs via asm "+v" (R2..R7 were paying
// per-iteration rematerialized global reloads: FETCH_SIZE ~10MB vs 16KB
// inputs, VGPR_Count 36 << live set, WRITE_SIZE ~0 rules out scratch);
// (2) mailbox ds_read pipelined TWO iterations ahead (mbA/mbB ping-pong,
// consumption lag KK+2, DELTA=73) so its latency is fully covered.

#define MM 2048
#define NN 2048
#define BR 8
#define BC 8
#define NT 256
#define NB (MM / BR)                 // 256 row-blocks
#define KK 8                         // barrier period (iterations)
#define DELTA (KK + 65)              // 73: skew between adjacent waves
#define MAXSKEW (63 + 3 * DELTA)     // 282
#define NITER (NB + MAXSKEW)         // 538
#define NSP ((NITER + KK - 1) / KK)  // 68 superphases
#define RING (2 * KK)                // 16 mailbox slots per boundary
#define INFV 1e30f

__device__ __forceinline__ float wave_shr1(float x) {
    int xi = __float_as_int(x);
    int r  = __builtin_amdgcn_update_dpp(xi, xi, 0x138 /*WAVE_SHR1*/, 0xF, 0xF, false);
    return __int_as_float(r);
}

__launch_bounds__(NT, 1)
__global__ void dtw_kernel(const float* __restrict__ src,
                           const float* __restrict__ tgt,
                           float* __restrict__ out)
{
    __shared__ float  s_srcT[BR * NB];   // transposed: [r][bi], stride-1 lane reads
    __shared__ float4 mbox[3][RING][2];  // wave-boundary right-column ring

    const int tid  = threadIdx.x;
    const int wv   = tid >> 6;
    const int ln   = tid & 63;
    const int skew = ln + wv * DELTA;

    for (int i = tid; i < MM; i += NT)
        s_srcT[(i & 7) * NB + (i >> 3)] = src[i];

    const float* tgp = tgt + tid * BC;
    float tg0 = tgp[0], tg1 = tgp[1], tg2 = tgp[2], tg3 = tgp[3],
          tg4 = tgp[4], tg5 = tgp[5], tg6 = tgp[6], tg7 = tgp[7];

    float cur0 = INFV, cur1 = INFV, cur2 = INFV, cur3 = INFV,
          cur4 = INFV, cur5 = INFV, cur6 = INFV, cur7 = INFV;

    float corner = (tid == 0) ? 0.0f : INFV;

    float rcp0 = INFV, rcp1 = INFV, rcp2 = INFV, rcp3 = INFV,
          rcp4 = INFV, rcp5 = INFV, rcp6 = INFV, rcp7 = INFV;

    float sh0 = INFV, sh1 = INFV, sh2 = INFV, sh3 = INFV,
          sh4 = INFV, sh5 = INFV, sh6 = INFV, sh7 = INFV;

    // two mailbox register sets (A for even iters, B for odd), INF until
    // first real value arrives (first active use is always post-write).
    float mbA0 = INFV, mbA1 = INFV, mbA2 = INFV, mbA3 = INFV,
          mbA4 = INFV, mbA5 = INFV, mbA6 = INFV, mbA7 = INFV;
    float mbB0 = INFV, mbB1 = INFV, mbB2 = INFV, mbB3 = INFV,
          mbB4 = INFV, mbB5 = INFV, mbB6 = INFV, mbB7 = INFV;

    float psA0, psA1, psA2, psA3, psA4, psA5, psA6, psA7;
    float psB0, psB1, psB2, psB3, psB4, psB5, psB6, psB7;

    __syncthreads();

    {
        int b0 = 0 - skew; if (b0 < 0) b0 = 0;
        int b1 = 1 - skew; if (b1 < 0) b1 = 0;
        const float* sa = s_srcT + b0;
        const float* sb = s_srcT + b1;
        psA0 = sa[0*NB]; psA1 = sa[1*NB]; psA2 = sa[2*NB]; psA3 = sa[3*NB];
        psA4 = sa[4*NB]; psA5 = sa[5*NB]; psA6 = sa[6*NB]; psA7 = sa[7*NB];
        psB0 = sb[0*NB]; psB1 = sb[1*NB]; psB2 = sb[2*NB]; psB3 = sb[3*NB];
        psB4 = sb[4*NB]; psB5 = sb[5*NB]; psB6 = sb[6*NB]; psB7 = sb[7*NB];
    }

#define CELL(CUR, TG) { float up = (CUR); float m = fminf(fminf(up, l), dgk); \
                        float d = sv - (TG); float v = fmaf(d, d, m);          \
                        dgk = up; (CUR) = v; l = v; }
#define ROWX(SV, LCV, DGV, RC) { float l = (LCV); float sv = (SV); float dgk = (DGV); \
        CELL(cur0, tg0) CELL(cur1, tg1) CELL(cur2, tg2) CELL(cur3, tg3)               \
        CELL(cur4, tg4) CELL(cur5, tg5) CELL(cur6, tg6) CELL(cur7, tg7)               \
        (RC) = l; }

// MB*: register set holding this iteration's wave-boundary value (loaded two
// iterations earlier); reloaded at the bottom for iteration n+2.
#define ITER(N_, P0,P1,P2,P3,P4,P5,P6,P7, MB0,MB1,MB2,MB3,MB4,MB5,MB6,MB7)            \
    {                                                                                 \
        const int n_ = (N_);                                                          \
        const bool z_ = (ln == 0);                                                    \
        float lc0 = z_ ? MB0 : sh0, lc1 = z_ ? MB1 : sh1;                             \
        float lc2 = z_ ? MB2 : sh2, lc3 = z_ ? MB3 : sh3;                             \
        float lc4 = z_ ? MB4 : sh4, lc5 = z_ ? MB5 : sh5;                             \
        float lc6 = z_ ? MB6 : sh6, lc7 = z_ ? MB7 : sh7;                             \
        const int bi_ = n_ - skew;                                                    \
        if (0 <= bi_ && bi_ < NB) {                                                   \
            float rc0, rc1, rc2, rc3, rc4, rc5, rc6, rc7;                             \
            ROWX(P0, lc0, corner, rc0)                                                \
            ROWX(P1, lc1, lc0,    rc1)                                                \
            ROWX(P2, lc2, lc1,    rc2)                                                \
            ROWX(P3, lc3, lc2,    rc3)                                                \
            ROWX(P4, lc4, lc3,    rc4)                                                \
            ROWX(P5, lc5, lc4,    rc5)                                                \
            ROWX(P6, lc6, lc5,    rc6)                                                \
            ROWX(P7, lc7, lc6,    rc7)                                                \
            corner = lc7;                                                             \
            rcp0 = rc0; rcp1 = rc1; rcp2 = rc2; rcp3 = rc3;                           \
            rcp4 = rc4; rcp5 = rc5; rcp6 = rc6; rcp7 = rc7;                           \
            if (ln == 63 && wv < 3) {                                                 \
                const int sl_ = n_ & (RING - 1);                                      \
                mbox[wv][sl_][0] = make_float4(rcp0, rcp1, rcp2, rcp3);               \
                mbox[wv][sl_][1] = make_float4(rcp4, rcp5, rcp6, rcp7);               \
            }                                                                         \
        }                                                                             \
        {   /* src prefetch for iteration n_+2 into the set just consumed */          \
            int bin_ = n_ + 2 - skew;                                                 \
            if (bin_ < 0) bin_ = 0;                                                   \
            if (bin_ > NB - 1) bin_ = NB - 1;                                         \
            const float* sp_ = s_srcT + bin_;                                         \
            P0 = sp_[0*NB]; P1 = sp_[1*NB]; P2 = sp_[2*NB]; P3 = sp_[3*NB];           \
            P4 = sp_[4*NB]; P5 = sp_[5*NB]; P6 = sp_[6*NB]; P7 = sp_[7*NB];           \
        }                                                                             \
        sh0 = wave_shr1(rcp0); sh1 = wave_shr1(rcp1);                                 \
        sh2 = wave_shr1(rcp2); sh3 = wave_shr1(rcp3);                                 \
        sh4 = wave_shr1(rcp4); sh5 = wave_shr1(rcp5);                                 \
        sh6 = wave_shr1(rcp6); sh7 = wave_shr1(rcp7);                                 \
        if (wv > 0) {  /* mailbox value for iteration n_+2 (consumed lag KK+2) */     \
            const int sl_ = (n_ - KK) & (RING - 1);                                   \
            float4 m0_ = mbox[wv - 1][sl_][0];                                        \
            float4 m1_ = mbox[wv - 1][sl_][1];                                        \
            MB0 = m0_.x; MB1 = m0_.y; MB2 = m0_.z; MB3 = m0_.w;                       \
            MB4 = m1_.x; MB5 = m1_.y; MB6 = m1_.z; MB7 = m1_.w;                       \
        }                                                                             \
    }

    for (int sp = 0; sp < NSP; ++sp) {
        const int n0 = sp * KK;
        #pragma unroll 1
        for (int it = 0; it < KK; it += 2) {
            // pin loop-invariants / pipelined sets in VGPRs: "+v" makes them
            // non-rematerializable (kills per-iteration global reloads)
            asm volatile("" : "+v"(tg0), "+v"(tg1), "+v"(tg2), "+v"(tg3),
                             "+v"(tg4), "+v"(tg5), "+v"(tg6), "+v"(tg7));
            asm volatile("" : "+v"(psA0), "+v"(psA1), "+v"(psA2), "+v"(psA3),
                             "+v"(psA4), "+v"(psA5), "+v"(psA6), "+v"(psA7));
            asm volatile("" : "+v"(psB0), "+v"(psB1), "+v"(psB2), "+v"(psB3),
                             "+v"(psB4), "+v"(psB5), "+v"(psB6), "+v"(psB7));
            ITER(n0 + it,     psA0,psA1,psA2,psA3,psA4,psA5,psA6,psA7,
                              mbA0,mbA1,mbA2,mbA3,mbA4,mbA5,mbA6,mbA7)
            ITER(n0 + it + 1, psB0,psB1,psB2,psB3,psB4,psB5,psB6,psB7,
                              mbB0,mbB1,mbB2,mbB3,mbB4,mbB5,mbB6,mbB7)
        }
        __syncthreads();
    }
#undef ITER
#undef ROWX
#undef CELL

    // tid 255 (wv=3,ln=63): block 255 computed at n = 255+282 = 537
    if (tid == NT - 1) out[0] = sqrtf(cur7);
}

extern "C" void kernel_launch(void* const* d_in, const int* in_sizes, int n_in,
                              void* d_out, int out_size, void* d_ws, size_t ws_size,
                              hipStream_t stream)
{
    (void)in_sizes; (void)n_in; (void)out_size; (void)d_ws; (void)ws_size;
    const float* source = (const float*)d_in[0];
    const float* target = (const float*)d_in[1];
    float* out = (float*)d_out;
    dtw_kernel<<<1, NT, 0, stream>>>(source, target, out);
}

// Round 9
// 266.243 us; speedup vs baseline: 1.0002x; 1.0002x over previous
//
#include <hip/hip_runtime.h>
#include <math.h>

// DTW 2048x2048, single workgroup of 256 threads (4 waves).
// Lane owns 8 columns; row-blocks of BR=8 rows; schedule identical to R8
// (KK=8 ring mailbox, DPP wave-shift exchange, 2-iter-ahead prefetch).
// R9 single change: the 64 cells of the 8x8 block are emitted in
// ANTI-DIAGONAL order with fully scalarized named registers -- 8
// independent min3->fma chains interleaved in program order, hiding the
// ~8 cyc/cell dependent-latency that made row-major a ~700 cyc serial
// chain per iteration (R3 tried this with arrays and hit scratch; R5-R8
// fixed scratch but were row-major: this is the untested combination).

#define MM 2048
#define NN 2048
#define BR 8
#define BC 8
#define NT 256
#define NB (MM / BR)                 // 256 row-blocks
#define KK 8                         // barrier period (iterations)
#define DELTA (KK + 65)              // 73: skew between adjacent waves
#define MAXSKEW (63 + 3 * DELTA)     // 282
#define NITER (NB + MAXSKEW)         // 538
#define NSP ((NITER + KK - 1) / KK)  // 68 superphases
#define RING (2 * KK)                // 16 mailbox slots per boundary
#define INFV 1e30f

__device__ __forceinline__ float wave_shr1(float x) {
    int xi = __float_as_int(x);
    int r  = __builtin_amdgcn_update_dpp(xi, xi, 0x138 /*WAVE_SHR1*/, 0xF, 0xF, false);
    return __int_as_float(r);
}

__launch_bounds__(NT, 1)
__global__ void dtw_kernel(const float* __restrict__ src,
                           const float* __restrict__ tgt,
                           float* __restrict__ out)
{
    __shared__ float  s_srcT[BR * NB];   // transposed: [r][bi], stride-1 lane reads
    __shared__ float4 mbox[3][RING][2];  // wave-boundary right-column ring

    const int tid  = threadIdx.x;
    const int wv   = tid >> 6;
    const int ln   = tid & 63;
    const int skew = ln + wv * DELTA;

    for (int i = tid; i < MM; i += NT)
        s_srcT[(i & 7) * NB + (i >> 3)] = src[i];

    const float* tgp = tgt + tid * BC;
    float tg0 = tgp[0], tg1 = tgp[1], tg2 = tgp[2], tg3 = tgp[3],
          tg4 = tgp[4], tg5 = tgp[5], tg6 = tgp[6], tg7 = tgp[7];

    float cur0 = INFV, cur1 = INFV, cur2 = INFV, cur3 = INFV,
          cur4 = INFV, cur5 = INFV, cur6 = INFV, cur7 = INFV;

    float corner = (tid == 0) ? 0.0f : INFV;

    float rcp0 = INFV, rcp1 = INFV, rcp2 = INFV, rcp3 = INFV,
          rcp4 = INFV, rcp5 = INFV, rcp6 = INFV, rcp7 = INFV;

    float sh0 = INFV, sh1 = INFV, sh2 = INFV, sh3 = INFV,
          sh4 = INFV, sh5 = INFV, sh6 = INFV, sh7 = INFV;

    float mbA0 = INFV, mbA1 = INFV, mbA2 = INFV, mbA3 = INFV,
          mbA4 = INFV, mbA5 = INFV, mbA6 = INFV, mbA7 = INFV;
    float mbB0 = INFV, mbB1 = INFV, mbB2 = INFV, mbB3 = INFV,
          mbB4 = INFV, mbB5 = INFV, mbB6 = INFV, mbB7 = INFV;

    float psA0, psA1, psA2, psA3, psA4, psA5, psA6, psA7;
    float psB0, psB1, psB2, psB3, psB4, psB5, psB6, psB7;

    __syncthreads();

    {
        int b0 = 0 - skew; if (b0 < 0) b0 = 0;
        int b1 = 1 - skew; if (b1 < 0) b1 = 0;
        const float* sa = s_srcT + b0;
        const float* sb = s_srcT + b1;
        psA0 = sa[0*NB]; psA1 = sa[1*NB]; psA2 = sa[2*NB]; psA3 = sa[3*NB];
        psA4 = sa[4*NB]; psA5 = sa[5*NB]; psA6 = sa[6*NB]; psA7 = sa[7*NB];
        psB0 = sb[0*NB]; psB1 = sb[1*NB]; psB2 = sb[2*NB]; psB3 = sb[3*NB];
        psB4 = sb[4*NB]; psB5 = sb[5*NB]; psB6 = sb[6*NB]; psB7 = sb[7*NB];
    }

// one cell (row R, col K) with source value SV; independent chain per row R
#define CEL(R, K, SV) { float up = cur##K;                                    \
                        float m  = fminf(fminf(up, l_##R), dg_##R);           \
                        float d  = (SV) - tg##K;                              \
                        float v  = fmaf(d, d, m);                             \
                        dg_##R = up; cur##K = v; l_##R = v; }

#define ITER(N_, P0,P1,P2,P3,P4,P5,P6,P7, MB0,MB1,MB2,MB3,MB4,MB5,MB6,MB7)            \
    {                                                                                 \
        const int n_ = (N_);                                                          \
        const bool z_ = (ln == 0);                                                    \
        float lc0 = z_ ? MB0 : sh0, lc1 = z_ ? MB1 : sh1;                             \
        float lc2 = z_ ? MB2 : sh2, lc3 = z_ ? MB3 : sh3;                             \
        float lc4 = z_ ? MB4 : sh4, lc5 = z_ ? MB5 : sh5;                             \
        float lc6 = z_ ? MB6 : sh6, lc7 = z_ ? MB7 : sh7;                             \
        const int bi_ = n_ - skew;                                                    \
        if (0 <= bi_ && bi_ < NB) {                                                   \
            float l_0 = lc0, l_1 = lc1, l_2 = lc2, l_3 = lc3;                         \
            float l_4 = lc4, l_5 = lc5, l_6 = lc6, l_7 = lc7;                         \
            float dg_0 = corner, dg_1 = lc0, dg_2 = lc1, dg_3 = lc2;                  \
            float dg_4 = lc3, dg_5 = lc4, dg_6 = lc5, dg_7 = lc6;                     \
            /* 15 anti-diagonals: cells within one diagonal are independent */        \
            CEL(0,0,P0)                                                               \
            CEL(0,1,P0) CEL(1,0,P1)                                                   \
            CEL(0,2,P0) CEL(1,1,P1) CEL(2,0,P2)                                       \
            CEL(0,3,P0) CEL(1,2,P1) CEL(2,1,P2) CEL(3,0,P3)                           \
            CEL(0,4,P0) CEL(1,3,P1) CEL(2,2,P2) CEL(3,1,P3) CEL(4,0,P4)               \
            CEL(0,5,P0) CEL(1,4,P1) CEL(2,3,P2) CEL(3,2,P3) CEL(4,1,P4) CEL(5,0,P5)   \
            CEL(0,6,P0) CEL(1,5,P1) CEL(2,4,P2) CEL(3,3,P3) CEL(4,2,P4) CEL(5,1,P5)   \
                CEL(6,0,P6)                                                           \
            CEL(0,7,P0) CEL(1,6,P1) CEL(2,5,P2) CEL(3,4,P3) CEL(4,3,P4) CEL(5,2,P5)   \
                CEL(6,1,P6) CEL(7,0,P7)                                               \
            CEL(1,7,P1) CEL(2,6,P2) CEL(3,5,P3) CEL(4,4,P4) CEL(5,3,P5) CEL(6,2,P6)   \
                CEL(7,1,P7)                                                           \
            CEL(2,7,P2) CEL(3,6,P3) CEL(4,5,P4) CEL(5,4,P5) CEL(6,3,P6) CEL(7,2,P7)   \
            CEL(3,7,P3) CEL(4,6,P4) CEL(5,5,P5) CEL(6,4,P6) CEL(7,3,P7)               \
            CEL(4,7,P4) CEL(5,6,P5) CEL(6,5,P6) CEL(7,4,P7)                           \
            CEL(5,7,P5) CEL(6,6,P6) CEL(7,5,P7)                                       \
            CEL(6,7,P6) CEL(7,6,P7)                                                   \
            CEL(7,7,P7)                                                               \
            corner = lc7;                                                             \
            rcp0 = l_0; rcp1 = l_1; rcp2 = l_2; rcp3 = l_3;                           \
            rcp4 = l_4; rcp5 = l_5; rcp6 = l_6; rcp7 = l_7;                           \
            if (ln == 63 && wv < 3) {                                                 \
                const int sl_ = n_ & (RING - 1);                                      \
                mbox[wv][sl_][0] = make_float4(rcp0, rcp1, rcp2, rcp3);               \
                mbox[wv][sl_][1] = make_float4(rcp4, rcp5, rcp6, rcp7);               \
            }                                                                         \
        }                                                                             \
        {   /* src prefetch for iteration n_+2 into the set just consumed */          \
            int bin_ = n_ + 2 - skew;                                                 \
            if (bin_ < 0) bin_ = 0;                                                   \
            if (bin_ > NB - 1) bin_ = NB - 1;                                         \
            const float* sp_ = s_srcT + bin_;                                         \
            P0 = sp_[0*NB]; P1 = sp_[1*NB]; P2 = sp_[2*NB]; P3 = sp_[3*NB];           \
            P4 = sp_[4*NB]; P5 = sp_[5*NB]; P6 = sp_[6*NB]; P7 = sp_[7*NB];           \
        }                                                                             \
        sh0 = wave_shr1(rcp0); sh1 = wave_shr1(rcp1);                                 \
        sh2 = wave_shr1(rcp2); sh3 = wave_shr1(rcp3);                                 \
        sh4 = wave_shr1(rcp4); sh5 = wave_shr1(rcp5);                                 \
        sh6 = wave_shr1(rcp6); sh7 = wave_shr1(rcp7);                                 \
        if (wv > 0) {  /* mailbox value for iteration n_+2 (consumed lag KK+2) */     \
            const int sl_ = (n_ - KK) & (RING - 1);                                   \
            float4 m0_ = mbox[wv - 1][sl_][0];                                        \
            float4 m1_ = mbox[wv - 1][sl_][1];                                        \
            MB0 = m0_.x; MB1 = m0_.y; MB2 = m0_.z; MB3 = m0_.w;                       \
            MB4 = m1_.x; MB5 = m1_.y; MB6 = m1_.z; MB7 = m1_.w;                       \
        }                                                                             \
    }

    for (int sp = 0; sp < NSP; ++sp) {
        const int n0 = sp * KK;
        #pragma unroll 1
        for (int it = 0; it < KK; it += 2) {
            asm volatile("" : "+v"(tg0), "+v"(tg1), "+v"(tg2), "+v"(tg3),
                             "+v"(tg4), "+v"(tg5), "+v"(tg6), "+v"(tg7));
            asm volatile("" : "+v"(psA0), "+v"(psA1), "+v"(psA2), "+v"(psA3),
                             "+v"(psA4), "+v"(psA5), "+v"(psA6), "+v"(psA7));
            asm volatile("" : "+v"(psB0), "+v"(psB1), "+v"(psB2), "+v"(psB3),
                             "+v"(psB4), "+v"(psB5), "+v"(psB6), "+v"(psB7));
            ITER(n0 + it,     psA0,psA1,psA2,psA3,psA4,psA5,psA6,psA7,
                              mbA0,mbA1,mbA2,mbA3,mbA4,mbA5,mbA6,mbA7)
            ITER(n0 + it + 1, psB0,psB1,psB2,psB3,psB4,psB5,psB6,psB7,
                              mbB0,mbB1,mbB2,mbB3,mbB4,mbB5,mbB6,mbB7)
        }
        __syncthreads();
    }
#undef ITER
#undef CEL

    // tid 255 (wv=3,ln=63): block 255 computed at n = 255+282 = 537
    if (tid == NT - 1) out[0] = sqrtf(cur7);
}

extern "C" void kernel_launch(void* const* d_in, const int* in_sizes, int n_in,
                              void* d_out, int out_size, void* d_ws, size_t ws_size,
                              hipStream_t stream)
{
    (void)in_sizes; (void)n_in; (void)out_size; (void)d_ws; (void)ws_size;
    const float* source = (const float*)d_in[0];
    const float* target = (const float*)d_in[1];
    float* out = (float*)d_out;
    dtw_kernel<<<1, NT, 0, stream>>>(source, target, out);
}

// Round 10
// 264.523 us; speedup vs baseline: 1.0067x; 1.0065x over previous
//
#include <hip/hip_runtime.h>
#include <math.h>

// DTW 2048x2048, single workgroup of 256 threads (4 waves).
// Lane owns 8 columns; row-blocks of BR=8 rows; schedule = R8/R9
// (KK=8 ring mailbox, DPP wave-shift exchange, 2-iter-ahead prefetch).
// R10: FULLY BRANCHLESS iteration body. R5-R9 sat at ~1190 cyc/iter with
// only ~500 cyc of issue; the gap is lgkmcnt(0) drains forced by the three
// conditional regions (compute guard, wv>0 mailbox read, ln==63 write),
// which make outstanding-LDS counts unknowable at merge points. Now:
//  - compute unconditional (ramp inputs are all INF -> outputs INF, which
//    ARE the correct boundary values; tail garbage never consumed; no NaN)
//  - mailbox read unconditional (wave w reads row (w+3)&3; a threshold
//    cndmask forces INFV for wave0 / ramp, also killing stale-LDS reads)
//  - mailbox write unconditional (lanes!=63 write to a dump array;
//    16B lane stride = uniform bank coverage, no conflict penalty)
// Static 12 DS ops/iter -> compiler can emit counted lgkmcnt with a full
// iteration of slack. Result captured via (bi==NB-1) select since the
// tail now overwrites cur.

#define MM 2048
#define NN 2048
#define BR 8
#define BC 8
#define NT 256
#define NB (MM / BR)                 // 256 row-blocks
#define KK 8                         // barrier period (iterations)
#define DELTA (KK + 65)              // 73: skew between adjacent waves
#define MAXSKEW (63 + 3 * DELTA)     // 282
#define NITER (NB + MAXSKEW)         // 538
#define NSP ((NITER + KK - 1) / KK)  // 68 superphases
#define RING (2 * KK)                // 16 mailbox slots per boundary
#define INFV 1e30f

__device__ __forceinline__ float wave_shr1(float x) {
    int xi = __float_as_int(x);
    int r  = __builtin_amdgcn_update_dpp(xi, xi, 0x138 /*WAVE_SHR1*/, 0xF, 0xF, false);
    return __int_as_float(r);
}

__launch_bounds__(NT, 1)
__global__ void dtw_kernel(const float* __restrict__ src,
                           const float* __restrict__ tgt,
                           float* __restrict__ out)
{
    __shared__ float  s_srcT[BR * NB];    // transposed: [r][bi]
    __shared__ float4 mbox[4][RING][2];   // row w written by wave w; read row (w+3)&3
    __shared__ float4 dump[64];           // throwaway writes, lanes != 63

    const int tid  = threadIdx.x;
    const int wv   = tid >> 6;
    const int ln   = tid & 63;
    const int skew = ln + wv * DELTA;
    const int mbthr = (wv == 0) ? 0x7fffffff : 0;  // lane0 mb gate: wv0 always INF, else ramp only
    const bool lz  = (ln == 0);
    const bool lw  = (ln == 63);

    for (int i = tid; i < MM; i += NT)
        s_srcT[(i & 7) * NB + (i >> 3)] = src[i];

    const float* tgp = tgt + tid * BC;
    float tg0 = tgp[0], tg1 = tgp[1], tg2 = tgp[2], tg3 = tgp[3],
          tg4 = tgp[4], tg5 = tgp[5], tg6 = tgp[6], tg7 = tgp[7];

    float cur0 = INFV, cur1 = INFV, cur2 = INFV, cur3 = INFV,
          cur4 = INFV, cur5 = INFV, cur6 = INFV, cur7 = INFV;

    float corner = (tid == 0) ? 0.0f : INFV;

    float rcp0 = INFV, rcp1 = INFV, rcp2 = INFV, rcp3 = INFV,
          rcp4 = INFV, rcp5 = INFV, rcp6 = INFV, rcp7 = INFV;

    float sh0 = INFV, sh1 = INFV, sh2 = INFV, sh3 = INFV,
          sh4 = INFV, sh5 = INFV, sh6 = INFV, sh7 = INFV;

    float mbA0 = INFV, mbA1 = INFV, mbA2 = INFV, mbA3 = INFV,
          mbA4 = INFV, mbA5 = INFV, mbA6 = INFV, mbA7 = INFV;
    float mbB0 = INFV, mbB1 = INFV, mbB2 = INFV, mbB3 = INFV,
          mbB4 = INFV, mbB5 = INFV, mbB6 = INFV, mbB7 = INFV;

    float psA0, psA1, psA2, psA3, psA4, psA5, psA6, psA7;
    float psB0, psB1, psB2, psB3, psB4, psB5, psB6, psB7;

    float res = 0.0f;

    float4* const mwrow = &mbox[wv][0][0];           // my write row
    const float4* const mrrow = &mbox[(wv + 3) & 3][0][0];  // my read row
    float4* const dmp = &dump[ln];

    __syncthreads();

    {
        int b0 = 0 - skew; if (b0 < 0) b0 = 0;
        int b1 = 1 - skew; if (b1 < 0) b1 = 0;
        const float* sa = s_srcT + b0;
        const float* sb = s_srcT + b1;
        psA0 = sa[0*NB]; psA1 = sa[1*NB]; psA2 = sa[2*NB]; psA3 = sa[3*NB];
        psA4 = sa[4*NB]; psA5 = sa[5*NB]; psA6 = sa[6*NB]; psA7 = sa[7*NB];
        psB0 = sb[0*NB]; psB1 = sb[1*NB]; psB2 = sb[2*NB]; psB3 = sb[3*NB];
        psB4 = sb[4*NB]; psB5 = sb[5*NB]; psB6 = sb[6*NB]; psB7 = sb[7*NB];
    }

// one cell (row R, col K) with source value SV; independent chain per row R
#define CEL(R, K, SV) { float up = cur##K;                                    \
                        float m  = fminf(fminf(up, l_##R), dg_##R);           \
                        float d  = (SV) - tg##K;                              \
                        float v  = fmaf(d, d, m);                             \
                        dg_##R = up; cur##K = v; l_##R = v; }

#define ITER(N_, P0,P1,P2,P3,P4,P5,P6,P7, MB0,MB1,MB2,MB3,MB4,MB5,MB6,MB7)            \
    {                                                                                 \
        const int n_ = (N_);                                                          \
        const int bi_ = n_ - skew;                                                    \
        const bool gm_ = (bi_ < mbthr);  /* force INFV: wave0 always, else ramp */    \
        float t0 = gm_ ? INFV : MB0, t1 = gm_ ? INFV : MB1;                           \
        float t2 = gm_ ? INFV : MB2, t3 = gm_ ? INFV : MB3;                           \
        float t4 = gm_ ? INFV : MB4, t5 = gm_ ? INFV : MB5;                           \
        float t6 = gm_ ? INFV : MB6, t7 = gm_ ? INFV : MB7;                           \
        float lc0 = lz ? t0 : sh0, lc1 = lz ? t1 : sh1;                               \
        float lc2 = lz ? t2 : sh2, lc3 = lz ? t3 : sh3;                               \
        float lc4 = lz ? t4 : sh4, lc5 = lz ? t5 : sh5;                               \
        float lc6 = lz ? t6 : sh6, lc7 = lz ? t7 : sh7;                               \
        float l_0 = lc0, l_1 = lc1, l_2 = lc2, l_3 = lc3;                             \
        float l_4 = lc4, l_5 = lc5, l_6 = lc6, l_7 = lc7;                             \
        float dg_0 = corner, dg_1 = lc0, dg_2 = lc1, dg_3 = lc2;                      \
        float dg_4 = lc3, dg_5 = lc4, dg_6 = lc5, dg_7 = lc6;                         \
        CEL(0,0,P0)                                                                   \
        CEL(0,1,P0) CEL(1,0,P1)                                                       \
        CEL(0,2,P0) CEL(1,1,P1) CEL(2,0,P2)                                           \
        CEL(0,3,P0) CEL(1,2,P1) CEL(2,1,P2) CEL(3,0,P3)                               \
        CEL(0,4,P0) CEL(1,3,P1) CEL(2,2,P2) CEL(3,1,P3) CEL(4,0,P4)                   \
        CEL(0,5,P0) CEL(1,4,P1) CEL(2,3,P2) CEL(3,2,P3) CEL(4,1,P4) CEL(5,0,P5)       \
        CEL(0,6,P0) CEL(1,5,P1) CEL(2,4,P2) CEL(3,3,P3) CEL(4,2,P4) CEL(5,1,P5)       \
            CEL(6,0,P6)                                                               \
        CEL(0,7,P0) CEL(1,6,P1) CEL(2,5,P2) CEL(3,4,P3) CEL(4,3,P4) CEL(5,2,P5)       \
            CEL(6,1,P6) CEL(7,0,P7)                                                   \
        CEL(1,7,P1) CEL(2,6,P2) CEL(3,5,P3) CEL(4,4,P4) CEL(5,3,P5) CEL(6,2,P6)       \
            CEL(7,1,P7)                                                               \
        CEL(2,7,P2) CEL(3,6,P3) CEL(4,5,P4) CEL(5,4,P5) CEL(6,3,P6) CEL(7,2,P7)       \
        CEL(3,7,P3) CEL(4,6,P4) CEL(5,5,P5) CEL(6,4,P6) CEL(7,3,P7)                   \
        CEL(4,7,P4) CEL(5,6,P5) CEL(6,5,P6) CEL(7,4,P7)                               \
        CEL(5,7,P5) CEL(6,6,P6) CEL(7,5,P7)                                           \
        CEL(6,7,P6) CEL(7,6,P7)                                                       \
        CEL(7,7,P7)                                                                   \
        corner = lc7;                                                                 \
        rcp0 = l_0; rcp1 = l_1; rcp2 = l_2; rcp3 = l_3;                               \
        rcp4 = l_4; rcp5 = l_5; rcp6 = l_6; rcp7 = l_7;                               \
        res = (bi_ == NB - 1) ? rcp7 : res;                                           \
        {   /* unconditional mailbox write: lane63 -> real slot, others -> dump */    \
            float4* wr = lw ? (mwrow + ((n_ & (RING - 1)) << 1)) : dmp;               \
            wr[0] = make_float4(rcp0, rcp1, rcp2, rcp3);                              \
            wr[1] = make_float4(rcp4, rcp5, rcp6, rcp7);                              \
        }                                                                             \
        {   /* src prefetch for iteration n_+2 */                                     \
            int bin_ = n_ + 2 - skew;                                                 \
            bin_ = (bin_ < 0) ? 0 : bin_;                                             \
            bin_ = (bin_ > NB - 1) ? NB - 1 : bin_;                                   \
            const float* sp_ = s_srcT + bin_;                                         \
            P0 = sp_[0*NB]; P1 = sp_[1*NB]; P2 = sp_[2*NB]; P3 = sp_[3*NB];           \
            P4 = sp_[4*NB]; P5 = sp_[5*NB]; P6 = sp_[6*NB]; P7 = sp_[7*NB];           \
        }                                                                             \
        sh0 = wave_shr1(rcp0); sh1 = wave_shr1(rcp1);                                 \
        sh2 = wave_shr1(rcp2); sh3 = wave_shr1(rcp3);                                 \
        sh4 = wave_shr1(rcp4); sh5 = wave_shr1(rcp5);                                 \
        sh6 = wave_shr1(rcp6); sh7 = wave_shr1(rcp7);                                 \
        {   /* unconditional mailbox read: value for iteration n_+2 */                \
            const int sl_ = (n_ + RING - KK) & (RING - 1);                            \
            float4 m0_ = mrrow[(sl_ << 1) + 0];                                       \
            float4 m1_ = mrrow[(sl_ << 1) + 1];                                       \
            MB0 = m0_.x; MB1 = m0_.y; MB2 = m0_.z; MB3 = m0_.w;                       \
            MB4 = m1_.x; MB5 = m1_.y; MB6 = m1_.z; MB7 = m1_.w;                       \
        }                                                                             \
    }

    for (int sp = 0; sp < NSP; ++sp) {
        const int n0 = sp * KK;
        #pragma unroll 1
        for (int it = 0; it < KK; it += 2) {
            ITER(n0 + it,     psA0,psA1,psA2,psA3,psA4,psA5,psA6,psA7,
                              mbA0,mbA1,mbA2,mbA3,mbA4,mbA5,mbA6,mbA7)
            ITER(n0 + it + 1, psB0,psB1,psB2,psB3,psB4,psB5,psB6,psB7,
                              mbB0,mbB1,mbB2,mbB3,mbB4,mbB5,mbB6,mbB7)
        }
        __syncthreads();
    }
#undef ITER
#undef CEL

    // tid 255 (wv=3,ln=63): block NB-1 computed at n = 255 + 282 = 537
    if (tid == NT - 1) out[0] = sqrtf(res);
}

extern "C" void kernel_launch(void* const* d_in, const int* in_sizes, int n_in,
                              void* d_out, int out_size, void* d_ws, size_t ws_size,
                              hipStream_t stream)
{
    (void)in_sizes; (void)n_in; (void)out_size; (void)d_ws; (void)ws_size;
    const float* source = (const float*)d_in[0];
    const float* target = (const float*)d_in[1];
    float* out = (float*)d_out;
    dtw_kernel<<<1, NT, 0, stream>>>(source, target, out);
}